// Round 8
// baseline (252.097 us; speedup 1.0000x reference)
//
#include <hip/hip_runtime.h>
#include <stdint.h>

// B=4, S=2048, H=16, Dh=64, model dim 1024. K,V inputs ignored (reference
// attends Q against itself).
#define S_LEN 2048
#define DH    64
#define NH    16
#define DM    1024
#define NBH   64
#define PP    72      // P row pitch in halves: 144 B rows, 16B-aligned, >=64 (R6 lesson)

typedef float    f32x4 __attribute__((ext_vector_type(4)));
typedef _Float16 half8 __attribute__((ext_vector_type(8)));
typedef _Float16 half4 __attribute__((ext_vector_type(4)));

// ---------- preprocess (R2-validated): fp32 Q -> f16 Qh [bh][s][d], QhT [bh][d][s] ----------
__global__ __launch_bounds__(256) void preprocess_kernel(const float* __restrict__ Q,
                                                         _Float16* __restrict__ Qh,
                                                         _Float16* __restrict__ QhT) {
    __shared__ _Float16 T[DH * 68];
    const int tid = threadIdx.x;
    const int st = blockIdx.x & 31;
    const int bh = blockIdx.x >> 5;
    const int b = bh >> 4, h = bh & 15;
    const float* src = Q + (size_t)b * S_LEN * DM + (size_t)(st * 64) * DM + h * DH;
    _Float16* qh_dst = Qh + ((size_t)bh * S_LEN + st * 64) * DH;
    _Float16* qt_dst = QhT + (size_t)bh * DH * S_LEN + st * 64;

    #pragma unroll
    for (int i = 0; i < 4; ++i) {
        const int lin = i * 256 + tid;
        const int sr  = lin >> 4;
        const int d4  = (lin & 15) * 4;
        const float4 v = *(const float4*)(src + (size_t)sr * DM + d4);
        const half4 hv = { (_Float16)v.x, (_Float16)v.y, (_Float16)v.z, (_Float16)v.w };
        *(half4*)(qh_dst + sr * DH + d4) = hv;
        T[(d4 + 0) * 68 + sr] = hv[0];
        T[(d4 + 1) * 68 + sr] = hv[1];
        T[(d4 + 2) * 68 + sr] = hv[2];
        T[(d4 + 3) * 68 + sr] = hv[3];
    }
    __syncthreads();
    #pragma unroll
    for (int i = 0; i < 4; ++i) {
        const int lin = i * 256 + tid;
        const int d   = lin >> 4;
        const int s4  = (lin & 15) * 4;
        const half4 tv = *(const half4*)&T[d * 68 + s4];
        *(half4*)(qt_dst + (size_t)d * S_LEN + s4) = tv;
    }
}

// ---------- attention v8: v7 loop + in-WG K-split x2 (4 waves/SIMD) ----------
// WG = 2 waves, both own the same 64 q rows; wave w covers keys [w*1024, +1024).
// Loop body identical to v7 (barrier-free, K/V frags from global, P via per-wave
// LDS pitch-72, l = P*ones MFMA). Epilogue: wave 1 dumps O(f16)+l into the spare
// space of its own P buffer; one barrier; wave 0 combines, normalizes, stores.
__global__ __launch_bounds__(128, 2) void attn_v8_kernel(const _Float16* __restrict__ Qh,
                                                         const _Float16* __restrict__ QhT,
                                                         float* __restrict__ out) {
    __shared__ __align__(16) _Float16 Pbuf[2 * 64 * PP];   // per-wave P [64 q][64 kj], 2 x 9 KB

    const int tid  = threadIdx.x;
    const int w    = tid >> 6;
    const int lane = tid & 63;
    const int quad = lane >> 4;
    const int l15  = lane & 15;

    // XCD-grouping swizzle: all 32 WGs of one bh share blockIdx%8 -> same XCD's L2.
    const int bi   = blockIdx.x;
    const int xcd  = bi & 7;
    const int slot = bi >> 3;              // 0..255
    const int bh   = xcd * 8 + (slot >> 5);
    const int qblk = slot & 31;
    const int q0   = qblk * 64;
    const int kb   = w * (S_LEN / 2);      // this wave's key half

    const _Float16* qh_bh = Qh + (size_t)bh * S_LEN * DH;
    const _Float16* qt_bh = QhT + (size_t)bh * DH * S_LEN;

    // Q register fragments (B-operand of S^T): lane holds Q[q=nch*16+l15][d=s*32+quad*8+j]
    half8 qreg[4][2];
    #pragma unroll
    for (int nch = 0; nch < 4; ++nch) {
        const _Float16* p = qh_bh + (size_t)(q0 + nch * 16 + l15) * DH + quad * 8;
        qreg[nch][0] = *(const half8*)p;
        qreg[nch][1] = *(const half8*)(p + 32);
    }

    // fixed per-column m = qs*||q||^2 — identical in both waves -> partials additive
    const float qs = 0.18033688011112042f;   // log2(e)/sqrt(64)
    float m_c[4];
    #pragma unroll
    for (int nch = 0; nch < 4; ++nch) {
        float part = 0.f;
        #pragma unroll
        for (int s = 0; s < 2; ++s)
            #pragma unroll
            for (int j = 0; j < 8; ++j) { const float x = (float)qreg[nch][s][j]; part += x * x; }
        part += __shfl_xor(part, 16, 64);
        part += __shfl_xor(part, 32, 64);
        m_c[nch] = qs * part;
    }

    half8 ones;
    #pragma unroll
    for (int j = 0; j < 8; ++j) ones[j] = (_Float16)1.0f;

    f32x4 O[4][4];                 // O[a=q-chunk][nch=d-chunk]
    #pragma unroll
    for (int a = 0; a < 4; ++a)
        #pragma unroll
        for (int n = 0; n < 4; ++n) O[a][n] = (f32x4){0.f, 0.f, 0.f, 0.f};
    f32x4 Lacc[4];                 // row-sums of P, same C-layout rows as O[a][*]
    #pragma unroll
    for (int a = 0; a < 4; ++a) Lacc[a] = (f32x4){0.f, 0.f, 0.f, 0.f};

    _Float16* Pw = &Pbuf[w * 64 * PP];
    const _Float16* knA = qh_bh + (size_t)(kb + l15) * DH + quad * 8;   // + (t*64 + mch*16)*DH
    const _Float16* vtA = qt_bh + (size_t)l15 * S_LEN + kb + quad * 8;  // + nch*16*S_LEN + t*64 (+32)

    for (int t = 0; t < 16; ++t) {
        // ---- S^T = K Q^T, K-frags straight from global (L1/L2-resident) ----
        #pragma unroll
        for (int mch = 0; mch < 4; ++mch) {
            const _Float16* kp = knA + (size_t)(t * 64 + mch * 16) * DH;
            const half8 a0 = *(const half8*)kp;
            const half8 a1 = *(const half8*)(kp + 32);
            #pragma unroll
            for (int nch = 0; nch < 4; ++nch) {
                f32x4 acc = (f32x4){0.f, 0.f, 0.f, 0.f};
                acc = __builtin_amdgcn_mfma_f32_16x16x32_f16(a0, qreg[nch][0], acc, 0, 0, 0);
                acc = __builtin_amdgcn_mfma_f32_16x16x32_f16(a1, qreg[nch][1], acc, 0, 0, 0);
                const float p0 = __builtin_amdgcn_exp2f(__builtin_fmaf(acc[0], qs, -m_c[nch]));
                const float p1 = __builtin_amdgcn_exp2f(__builtin_fmaf(acc[1], qs, -m_c[nch]));
                const float p2 = __builtin_amdgcn_exp2f(__builtin_fmaf(acc[2], qs, -m_c[nch]));
                const float p3 = __builtin_amdgcn_exp2f(__builtin_fmaf(acc[3], qs, -m_c[nch]));
                const half4 hv = (half4){ (_Float16)p0, (_Float16)p1, (_Float16)p2, (_Float16)p3 };
                *(half4*)&Pw[(nch * 16 + l15) * PP + mch * 16 + quad * 4] = hv;
            }
        }

        // ---- P back as A-frags (same-wave LDS roundtrip: lgkmcnt only) ----
        half8 pf[4][2];
        #pragma unroll
        for (int a = 0; a < 4; ++a) {
            pf[a][0] = *(const half8*)&Pw[(a * 16 + l15) * PP + quad * 8];
            pf[a][1] = *(const half8*)&Pw[(a * 16 + l15) * PP + 32 + quad * 8];
        }

        // ---- l += P * ones (row-sum in C-layout, no VALU) ----
        #pragma unroll
        for (int a = 0; a < 4; ++a) {
            Lacc[a] = __builtin_amdgcn_mfma_f32_16x16x32_f16(pf[a][0], ones, Lacc[a], 0, 0, 0);
            Lacc[a] = __builtin_amdgcn_mfma_f32_16x16x32_f16(pf[a][1], ones, Lacc[a], 0, 0, 0);
        }

        // ---- O += P V, V-frags straight from global QhT ----
        #pragma unroll
        for (int nch = 0; nch < 4; ++nch) {
            const _Float16* vp = vtA + (size_t)(nch * 16) * S_LEN + t * 64;
            const half8 v0 = *(const half8*)vp;
            const half8 v1 = *(const half8*)(vp + 32);
            #pragma unroll
            for (int a = 0; a < 4; ++a) {
                O[a][nch] = __builtin_amdgcn_mfma_f32_16x16x32_f16(pf[a][0], v0, O[a][nch], 0, 0, 0);
                O[a][nch] = __builtin_amdgcn_mfma_f32_16x16x32_f16(pf[a][1], v1, O[a][nch], 0, 0, 0);
            }
        }
    }

    // ---- in-WG partial combine ----
    // Wave 1 writes into the spare space of ITS OWN P buffer (same-wave DS ordering:
    // safe without a pre-barrier). Layout: O as f16, [q-row][d], pitch 68 (row*34+col/2
    // spreads quads across banks -> 2-way max). l (fp32, 64 vals) in the 512 B tail.
    _Float16* obx = &Pbuf[64 * PP];                   // wave-1 region
    float*    Lx  = (float*)&Pbuf[64 * PP + 64 * 68]; // 256 spare halves = 64 floats ok
    if (w == 1) {
        #pragma unroll
        for (int a = 0; a < 4; ++a) {
            #pragma unroll
            for (int nch = 0; nch < 4; ++nch)
                #pragma unroll
                for (int r = 0; r < 4; ++r)
                    obx[(a * 16 + quad * 4 + r) * 68 + nch * 16 + l15] = (_Float16)O[a][nch][r];
            if (l15 == 0)
                #pragma unroll
                for (int r = 0; r < 4; ++r)
                    Lx[a * 16 + quad * 4 + r] = Lacc[a][r];
        }
    }
    __syncthreads();
    if (w == 0) {
        #pragma unroll
        for (int a = 0; a < 4; ++a)
            #pragma unroll
            for (int nch = 0; nch < 4; ++nch)
                #pragma unroll
                for (int r = 0; r < 4; ++r)
                    O[a][nch][r] += (float)obx[(a * 16 + quad * 4 + r) * 68 + nch * 16 + l15];

        const int b = bh >> 4, h = bh & 15;
        float* ob = out + (size_t)b * S_LEN * DM + h * DH;
        #pragma unroll
        for (int a = 0; a < 4; ++a) {
            float inv[4];
            #pragma unroll
            for (int r = 0; r < 4; ++r)
                inv[r] = 1.0f / (Lacc[a][r] + Lx[a * 16 + quad * 4 + r]);
            #pragma unroll
            for (int nch = 0; nch < 4; ++nch)
                #pragma unroll
                for (int r = 0; r < 4; ++r)
                    ob[(size_t)(q0 + a * 16 + quad * 4 + r) * DM + nch * 16 + l15] = O[a][nch][r] * inv[r];
        }
    }
}

extern "C" void kernel_launch(void* const* d_in, const int* in_sizes, int n_in,
                              void* d_out, int out_size, void* d_ws, size_t ws_size,
                              hipStream_t stream) {
    const float* Q = (const float*)d_in[0];   // K, V ignored per reference
    float* out = (float*)d_out;
    _Float16* Qh  = (_Float16*)d_ws;                      // 16 MiB
    _Float16* QhT = Qh + (size_t)NBH * S_LEN * DH;        // 16 MiB (ws >= 32 MiB verified R2-R7)
    preprocess_kernel<<<dim3(NBH * (S_LEN / 64)), dim3(256), 0, stream>>>(Q, Qh, QhT);
    attn_v8_kernel<<<dim3(NBH * (S_LEN / 64)), dim3(128), 0, stream>>>(Qh, QhT, out);
}